// Round 3
// baseline (336.485 us; speedup 1.0000x reference)
//
#include <hip/hip_runtime.h>

// SSIM loss, fused single-pass kernel. 96 planes of 512x512.
// 64x64 output tile per block, 256 threads; each thread: 2 adjacent
// columns x 8 rows = 16 output pixels. Separable 11-tap Gaussian.
//
// R3: NO ARRAYS in the per-thread hot path. R1/R2 both reported
// VGPR_Count=68 -> the acc[8][5]/tp[12] arrays stayed in scratch
// (SROA failed), VALUBusy fell to 63% on scratch stalls. Here every
// accumulator is a named scalar and the 18-row j-loop + vertical
// scatter is preprocessor-expanded with literal weights, so the
// whole dataflow is SSA from the front-end on.

typedef float v2f __attribute__((ext_vector_type(2)));
typedef float v4f __attribute__((ext_vector_type(4)));

#define IMG 512
#define TILE 64
#define HALO 5
#define LROWS 74            // TILE + 2*HALO
#define LCOLS 74
#define LSTRIDE 76          // v2f stride; even -> 16B-aligned v4f reads
#define LSTRIDE4 38         // LSTRIDE/2, in v4f units
#define NPIX 25165824.0     // 32*3*512*512

// Gaussian(sigma=1.5, 11 taps), normalized, fp32 (verified absmax 0.0 in R1/R2)
#define WTAP0  0.00102838f
#define WTAP1  0.00759876f
#define WTAP2  0.03600077f
#define WTAP3  0.10936068f
#define WTAP4  0.21300552f
#define WTAP5  0.26601173f
#define WTAP6  0.21300552f
#define WTAP7  0.10936068f
#define WTAP8  0.03600077f
#define WTAP9  0.00759876f
#define WTAP10 0.00102838f

// Declare per-output-row accumulators (col0 / col1; mu=(mu1,mu2) packed,
// pp=(E[x^2],E[y^2]) packed, xy=E[xy] scalar)
#define DECL(o) \
    v2f amu0_##o = {0.f,0.f}, amu1_##o = {0.f,0.f}; \
    v2f app0_##o = {0.f,0.f}, app1_##o = {0.f,0.f}; \
    float axy0_##o = 0.f, axy1_##o = 0.f;

// One interior horizontal tap feeding both columns (wA: col0 weight, wB: col1)
#define TAPB(ex, ey, wA, wB) { \
    v2f t = {ex, ey}; v2f pp = t * t; float xy = (ex) * (ey); \
    hmu0 += wA * t; hpp0 += wA * pp; hxy0 += wA * xy; \
    hmu1 += wB * t; hpp1 += wB * pp; hxy1 += wB * xy; }

// Vertical scatter of this row's h-sums into output row o with weight w
#define UPD(o, w) \
    amu0_##o += (w) * hmu0; amu1_##o += (w) * hmu1; \
    app0_##o += (w) * hpp0; app1_##o += (w) * hpp1; \
    axy0_##o += (w) * hxy0; axy1_##o += (w) * hxy1;

// One LDS input row: 6x ds_read_b128 (12 taps = both columns' windows),
// horizontal 11-tap conv for both columns, then the pasted UPD list.
#define JROW(J, ...) { \
    const v4f* bp = tile4 + (r0 + (J)) * LSTRIDE4 + cpair; \
    v4f q0 = bp[0], q1 = bp[1], q2 = bp[2], q3 = bp[3], q4 = bp[4], q5 = bp[5]; \
    v2f hmu0, hmu1, hpp0, hpp1; float hxy0, hxy1; \
    { v2f t = {q0.x, q0.y}; v2f pp = t * t; float xy = q0.x * q0.y; \
      hmu0 = WTAP0 * t; hpp0 = WTAP0 * pp; hxy0 = WTAP0 * xy; \
      hmu1 = (v2f){0.f,0.f}; hpp1 = (v2f){0.f,0.f}; hxy1 = 0.f; } \
    TAPB(q0.z, q0.w, WTAP1,  WTAP0) \
    TAPB(q1.x, q1.y, WTAP2,  WTAP1) \
    TAPB(q1.z, q1.w, WTAP3,  WTAP2) \
    TAPB(q2.x, q2.y, WTAP4,  WTAP3) \
    TAPB(q2.z, q2.w, WTAP5,  WTAP4) \
    TAPB(q3.x, q3.y, WTAP6,  WTAP5) \
    TAPB(q3.z, q3.w, WTAP7,  WTAP6) \
    TAPB(q4.x, q4.y, WTAP8,  WTAP7) \
    TAPB(q4.z, q4.w, WTAP9,  WTAP8) \
    TAPB(q5.x, q5.y, WTAP10, WTAP9) \
    { v2f t = {q5.z, q5.w}; v2f pp = t * t; float xy = q5.z * q5.w; \
      hmu1 += WTAP10 * t; hpp1 += WTAP10 * pp; hxy1 += WTAP10 * xy; } \
    __VA_ARGS__ }

__device__ __forceinline__ float ssim_px(v2f amu, v2f app, float exy)
{
    const float C1 = 1e-4f;   // 0.01^2
    const float C2 = 9e-4f;   // 0.03^2
    float mu1 = amu.x, mu2 = amu.y;
    float mu1s = mu1 * mu1;
    float mu2s = mu2 * mu2;
    float mu12 = mu1 * mu2;
    float s1 = app.x - mu1s;
    float s2 = app.y - mu2s;
    float s12 = exy - mu12;
    float num = (2.f * mu12 + C1) * (2.f * s12 + C2);
    float den = (mu1s + mu2s + C1) * (s1 + s2 + C2);
    return num * __builtin_amdgcn_rcpf(den);
}

#define FINAL(o) \
    lsum += ssim_px(amu0_##o, app0_##o, axy0_##o); \
    lsum += ssim_px(amu1_##o, app1_##o, axy1_##o);

__global__ __launch_bounds__(256, 3) void ssim_main(
    const float* __restrict__ clean,
    const float* __restrict__ adv,
    double* __restrict__ accum)
{
    __shared__ __align__(16) v2f tile[LROWS * LSTRIDE];
    __shared__ float wpart[4];

    const int tid = threadIdx.x;
    const int b = blockIdx.x;
    const int plane = b >> 6;         // 64 tiles per plane
    const int t6 = b & 63;
    const int tile_x = (t6 & 7) * TILE;
    const int tile_y = (t6 >> 3) * TILE;

    const float* __restrict__ cp = clean + (size_t)plane * (IMG * IMG);
    const float* __restrict__ ap = adv   + (size_t)plane * (IMG * IMG);

    // ---- Stage haloed tile (zero-padded at plane edges) ----
    for (int idx = tid; idx < LROWS * LCOLS; idx += 256) {
        int r = idx / LCOLS;
        int c = idx - r * LCOLS;
        int gr = tile_y + r - HALO;
        int gc = tile_x + c - HALO;
        v2f v = {0.f, 0.f};
        if (gr >= 0 && gr < IMG && gc >= 0 && gc < IMG) {
            int gi = gr * IMG + gc;
            v.x = cp[gi];
            v.y = ap[gi];
        }
        tile[r * LSTRIDE + c] = v;
    }
    __syncthreads();

    // ---- Compute ----
    const int cpair = tid & 31;       // output cols 2*cpair, 2*cpair+1
    const int trow = tid >> 5;        // 0..7
    const int r0 = trow * 8;          // output rows r0..r0+7 (tile coords)
    const v4f* __restrict__ tile4 = (const v4f*)tile;

    DECL(0) DECL(1) DECL(2) DECL(3) DECL(4) DECL(5) DECL(6) DECL(7)

    // 18 input rows; vertical weights statically woven (kv = j - o)
    JROW(0,  UPD(0,WTAP0))
    JROW(1,  UPD(0,WTAP1) UPD(1,WTAP0))
    JROW(2,  UPD(0,WTAP2) UPD(1,WTAP1) UPD(2,WTAP0))
    JROW(3,  UPD(0,WTAP3) UPD(1,WTAP2) UPD(2,WTAP1) UPD(3,WTAP0))
    JROW(4,  UPD(0,WTAP4) UPD(1,WTAP3) UPD(2,WTAP2) UPD(3,WTAP1) UPD(4,WTAP0))
    JROW(5,  UPD(0,WTAP5) UPD(1,WTAP4) UPD(2,WTAP3) UPD(3,WTAP2) UPD(4,WTAP1) UPD(5,WTAP0))
    JROW(6,  UPD(0,WTAP6) UPD(1,WTAP5) UPD(2,WTAP4) UPD(3,WTAP3) UPD(4,WTAP2) UPD(5,WTAP1) UPD(6,WTAP0))
    JROW(7,  UPD(0,WTAP7) UPD(1,WTAP6) UPD(2,WTAP5) UPD(3,WTAP4) UPD(4,WTAP3) UPD(5,WTAP2) UPD(6,WTAP1) UPD(7,WTAP0))
    JROW(8,  UPD(0,WTAP8) UPD(1,WTAP7) UPD(2,WTAP6) UPD(3,WTAP5) UPD(4,WTAP4) UPD(5,WTAP3) UPD(6,WTAP2) UPD(7,WTAP1))
    JROW(9,  UPD(0,WTAP9) UPD(1,WTAP8) UPD(2,WTAP7) UPD(3,WTAP6) UPD(4,WTAP5) UPD(5,WTAP4) UPD(6,WTAP3) UPD(7,WTAP2))
    JROW(10, UPD(0,WTAP10) UPD(1,WTAP9) UPD(2,WTAP8) UPD(3,WTAP7) UPD(4,WTAP6) UPD(5,WTAP5) UPD(6,WTAP4) UPD(7,WTAP3))
    JROW(11, UPD(1,WTAP10) UPD(2,WTAP9) UPD(3,WTAP8) UPD(4,WTAP7) UPD(5,WTAP6) UPD(6,WTAP5) UPD(7,WTAP4))
    JROW(12, UPD(2,WTAP10) UPD(3,WTAP9) UPD(4,WTAP8) UPD(5,WTAP7) UPD(6,WTAP6) UPD(7,WTAP5))
    JROW(13, UPD(3,WTAP10) UPD(4,WTAP9) UPD(5,WTAP8) UPD(6,WTAP7) UPD(7,WTAP6))
    JROW(14, UPD(4,WTAP10) UPD(5,WTAP9) UPD(6,WTAP8) UPD(7,WTAP7))
    JROW(15, UPD(5,WTAP10) UPD(6,WTAP9) UPD(7,WTAP8))
    JROW(16, UPD(6,WTAP10) UPD(7,WTAP9))
    JROW(17, UPD(7,WTAP10))

    // ---- SSIM formula + local sum ----
    float lsum = 0.f;
    FINAL(0) FINAL(1) FINAL(2) FINAL(3) FINAL(4) FINAL(5) FINAL(6) FINAL(7)

    // ---- Reduce: wave shuffle -> LDS -> one atomic per block ----
    #pragma unroll
    for (int off = 32; off > 0; off >>= 1)
        lsum += __shfl_down(lsum, off);
    const int lane = tid & 63;
    const int wave = tid >> 6;
    if (lane == 0) wpart[wave] = lsum;
    __syncthreads();
    if (tid == 0) {
        float bs = wpart[0] + wpart[1] + wpart[2] + wpart[3];
        atomicAdd(accum, (double)bs);
    }
}

__global__ void ssim_finalize(const double* __restrict__ accum,
                              float* __restrict__ out)
{
    if (threadIdx.x == 0) {
        out[0] = 1.f - (float)(accum[0] / NPIX);
    }
}

extern "C" void kernel_launch(void* const* d_in, const int* in_sizes, int n_in,
                              void* d_out, int out_size, void* d_ws, size_t ws_size,
                              hipStream_t stream)
{
    const float* clean = (const float*)d_in[0];
    const float* adv   = (const float*)d_in[1];
    float* out = (float*)d_out;
    double* accum = (double*)d_ws;

    hipMemsetAsync(accum, 0, sizeof(double), stream);

    const int nblocks = 96 * 64;   // 96 planes * (8x8 tiles of 64x64)
    ssim_main<<<nblocks, 256, 0, stream>>>(clean, adv, accum);
    ssim_finalize<<<1, 64, 0, stream>>>(accum, out);
}

// Round 4
// 311.639 us; speedup vs baseline: 1.0797x; 1.0797x over previous
//
#include <hip/hip_runtime.h>

// SSIM loss, fused single-pass kernel. 96 planes of 512x512.
// 64x64 output tile per block, 512 threads: 32 column-pairs x 16 row-strips,
// each thread 2 cols x 4 rows = 8 output px. Separable 11-tap Gaussian.
//
// R4 changes:
//  * s/d transform: stage {s=x+y, d=x-y}; convolve only 4 fields
//    {s,d} and {s^2,d^2} (SSIM needs only Exx+Eyy and Exy, recovered as
//    (P+Q)/2 and (P-Q)/4). Packs into exactly 2 v_pk_fma_f32 slots.
//  * RPT=4, 512 threads: 32 accumulator floats/thread (was 80).
//  * amdgpu_waves_per_eu(6,6): R1-R3 all allocated exactly 68 VGPRs
//    (allocator targeting ~7 waves/EU, ignoring the 45KB-LDS cap of
//    3 blocks/CU) and spilled ~110 live floats to AGPRs -> 2.5x VALU
//    bloat. max=6 licenses the allocator to use the registers; LDS
//    gives exactly 3 blocks x 8 waves = 24 waves/CU = 6/EU.

typedef float v2f __attribute__((ext_vector_type(2)));
typedef float v4f __attribute__((ext_vector_type(4)));

#define IMG 512
#define TILE 64
#define HALO 5
#define LROWS 74            // TILE + 2*HALO
#define LCOLS 74
#define LSTRIDE 76          // v2f stride; even -> 16B-aligned v4f reads
#define LSTRIDE4 38         // in v4f units
#define RPT 4               // output rows per thread
#define NPIX 25165824.0     // 32*3*512*512

// Gaussian(sigma=1.5, 11 taps), normalized, fp32 (absmax 0.0 in R1-R3)
__device__ constexpr float WT[11] = {
    0.00102838f, 0.00759876f, 0.03600077f, 0.10936068f, 0.21300552f,
    0.26601173f,
    0.21300552f, 0.10936068f, 0.03600077f, 0.00759876f, 0.00102838f};

__global__ __launch_bounds__(512)
__attribute__((amdgpu_waves_per_eu(6, 6)))
void ssim_main(const float* __restrict__ clean,
               const float* __restrict__ adv,
               double* __restrict__ accum)
{
    __shared__ __align__(16) v2f tile[LROWS * LSTRIDE];
    __shared__ float wpart[8];

    const int tid = threadIdx.x;
    const int b = blockIdx.x;
    const int plane = b >> 6;         // 64 tiles per plane
    const int t6 = b & 63;
    const int tile_x = (t6 & 7) * TILE;
    const int tile_y = (t6 >> 3) * TILE;

    const float* __restrict__ cp = clean + (size_t)plane * (IMG * IMG);
    const float* __restrict__ ap = adv   + (size_t)plane * (IMG * IMG);

    // ---- Stage haloed tile as {s=x+y, d=x-y} (zero-padded at edges) ----
    for (int idx = tid; idx < LROWS * LCOLS; idx += 512) {
        int r = idx / LCOLS;
        int c = idx - r * LCOLS;
        int gr = tile_y + r - HALO;
        int gc = tile_x + c - HALO;
        v2f v = {0.f, 0.f};
        if (gr >= 0 && gr < IMG && gc >= 0 && gc < IMG) {
            int gi = gr * IMG + gc;
            float x = cp[gi];
            float y = ap[gi];
            v.x = x + y;
            v.y = x - y;
        }
        tile[r * LSTRIDE + c] = v;
    }
    __syncthreads();

    // ---- Compute ----
    const int cpair = tid & 31;       // output cols 2*cpair, 2*cpair+1
    const int strip = tid >> 5;       // 0..15
    const int r0 = strip * RPT;       // output rows r0..r0+3 (tile coords)
    const v4f* __restrict__ tile4 = (const v4f*)tile;

    // Per output row: aA = conv{s,d}, aB = conv{s^2,d^2}; suffix 0/1 = col
    v2f aA0[RPT], aA1[RPT], aB0[RPT], aB1[RPT];
    #pragma unroll
    for (int o = 0; o < RPT; ++o) {
        aA0[o] = (v2f){0.f, 0.f}; aA1[o] = (v2f){0.f, 0.f};
        aB0[o] = (v2f){0.f, 0.f}; aB1[o] = (v2f){0.f, 0.f};
    }

    // Input rows r0..r0+13 (output row r uses input rows r..r+10)
    #pragma unroll
    for (int j = 0; j < RPT + 10; ++j) {
        const v4f* bp = tile4 + (r0 + j) * LSTRIDE4 + cpair;
        v4f q0 = bp[0], q1 = bp[1], q2 = bp[2], q3 = bp[3], q4 = bp[4], q5 = bp[5];
        v2f t[12];
        t[0]  = (v2f){q0.x, q0.y}; t[1]  = (v2f){q0.z, q0.w};
        t[2]  = (v2f){q1.x, q1.y}; t[3]  = (v2f){q1.z, q1.w};
        t[4]  = (v2f){q2.x, q2.y}; t[5]  = (v2f){q2.z, q2.w};
        t[6]  = (v2f){q3.x, q3.y}; t[7]  = (v2f){q3.z, q3.w};
        t[8]  = (v2f){q4.x, q4.y}; t[9]  = (v2f){q4.z, q4.w};
        t[10] = (v2f){q5.x, q5.y}; t[11] = (v2f){q5.z, q5.w};

        // Horizontal conv, both columns (col0: taps 0..10, col1: 1..11)
        v2f hA0 = {0.f, 0.f}, hA1 = {0.f, 0.f};
        v2f hB0 = {0.f, 0.f}, hB1 = {0.f, 0.f};
        #pragma unroll
        for (int k = 0; k < 12; ++k) {
            v2f tv = t[k];
            v2f pp = tv * tv;         // {s^2, d^2}
            if (k < 11) {
                const float w = WT[k];
                hA0 += w * tv; hB0 += w * pp;
            }
            if (k > 0) {
                const float w = WT[k - 1];
                hA1 += w * tv; hB1 += w * pp;
            }
        }

        // Vertical scatter (kv compile-time after unroll)
        #pragma unroll
        for (int o = 0; o < RPT; ++o) {
            const int kv = j - o;
            if (kv >= 0 && kv < 11) {
                const float w = WT[kv];
                aA0[o] += w * hA0; aA1[o] += w * hA1;
                aB0[o] += w * hB0; aB1[o] += w * hB1;
            }
        }
    }

    // ---- SSIM formula + local sum ----
    // u=conv(s), v=conv(d), P=conv(s^2), Q=conv(d^2), U=u^2, V=v^2:
    //   2*mu12       = (U-V)/2        mu1^2+mu2^2 = (U+V)/2
    //   2*sigma12    = (P-Q)/2-(U-V)/2
    //   sig1^2+sig2^2= (P+Q)/2-(U+V)/2
    const float C1 = 1e-4f;   // 0.01^2
    const float C2 = 9e-4f;   // 0.03^2
    float lsum = 0.f;
    #pragma unroll
    for (int o = 0; o < RPT; ++o) {
        #pragma unroll
        for (int s = 0; s < 2; ++s) {
            v2f a  = s ? aA1[o] : aA0[o];
            v2f bb = s ? aB1[o] : aB0[o];
            float U = a.x * a.x;
            float V = a.y * a.y;
            float halfUmV = 0.5f * (U - V);
            float halfUpV = 0.5f * (U + V);
            float num1 = halfUmV + C1;
            float num2 = 0.5f * (bb.x - bb.y) - halfUmV + C2;
            float den1 = halfUpV + C1;
            float den2 = 0.5f * (bb.x + bb.y) - halfUpV + C2;
            lsum += (num1 * num2) * __builtin_amdgcn_rcpf(den1 * den2);
        }
    }

    // ---- Reduce: wave shuffle -> LDS -> one atomic per block ----
    #pragma unroll
    for (int off = 32; off > 0; off >>= 1)
        lsum += __shfl_down(lsum, off);
    const int lane = tid & 63;
    const int wave = tid >> 6;        // 0..7
    if (lane == 0) wpart[wave] = lsum;
    __syncthreads();
    if (tid == 0) {
        float bs = 0.f;
        #pragma unroll
        for (int w = 0; w < 8; ++w) bs += wpart[w];
        atomicAdd(accum, (double)bs);
    }
}

__global__ void ssim_finalize(const double* __restrict__ accum,
                              float* __restrict__ out)
{
    if (threadIdx.x == 0) {
        out[0] = 1.f - (float)(accum[0] / NPIX);
    }
}

extern "C" void kernel_launch(void* const* d_in, const int* in_sizes, int n_in,
                              void* d_out, int out_size, void* d_ws, size_t ws_size,
                              hipStream_t stream)
{
    const float* clean = (const float*)d_in[0];
    const float* adv   = (const float*)d_in[1];
    float* out = (float*)d_out;
    double* accum = (double*)d_ws;

    hipMemsetAsync(accum, 0, sizeof(double), stream);

    const int nblocks = 96 * 64;   // 96 planes * (8x8 tiles of 64x64)
    ssim_main<<<nblocks, 512, 0, stream>>>(clean, adv, accum);
    ssim_finalize<<<1, 64, 0, stream>>>(accum, out);
}